// Round 10
// baseline (386.246 us; speedup 1.0000x reference)
//
#include <hip/hip_runtime.h>
#include <math.h>

#define NNODES 50000
#define NEDGES 800000
#define NSB 49       // scan blocks: ceil(50000/1024)
#define NPACK 640    // weight-pack blocks
#define NCVT 3125    // x->bf16 convert blocks: 50000*256/(256*16)
#define EBH 3125     // hist blocks: 800000/256
#define NBMW 782     // gemm_wide row-tile blocks: ceil(50000/64)  (64-row tiles, 256 thr)
#define NBML 391     // gemm_l2 row-tile blocks: ceil(50000/128)
#define SCB 3125     // scatter blocks @256: ceil(800000/256)
#define NBA 6250     // agg blocks: 8 nodes/block (2 per wave), 6250*8 = 50000 exact

__device__ __forceinline__ float leaky(float x) { return x > 0.f ? x : 0.2f * x; }

__device__ __forceinline__ ushort f2bf(float f) {
    unsigned u = __float_as_uint(f);
    return (ushort)((u + 0x7fffu + ((u >> 16) & 1u)) >> 16);  // RNE
}
__device__ __forceinline__ float bf2f(ushort u) {
    return __uint_as_float((unsigned)u << 16);
}

typedef const __attribute__((address_space(1))) void* gptr_t;
typedef __attribute__((address_space(3))) void* lptr_t;

// featb layout (H=4 layers): FLAT head-major, col n = h*64 + d  (the GEMM's native
// B-column order). agg4 lane li consumes cols [li*8, li*8+8) -> all one head (li>>3),
// so the per-edge weight is a scalar and resid/bias/out are 16B-contiguous per lane.

// ---- front: hist(+perm) | weight pack | x->bf16 convert (independent work, one dispatch) ----
// Hist atomic's return value IS the within-node sequence number -> saved as perm[e],
// making the later CSR scatter atomic-free.
__global__ __launch_bounds__(256) void front_kernel(
    const int* __restrict__ dst, int* __restrict__ counts, ushort* __restrict__ perm,
    const float* __restrict__ W0, const float* __restrict__ W1, const float* __restrict__ W2,
    const float* __restrict__ Wr, ushort* __restrict__ Bt0, ushort* __restrict__ Bt1,
    ushort* __restrict__ Bt2, const float* __restrict__ x, ushort* __restrict__ xb) {
    using ushort8v = __attribute__((ext_vector_type(8))) unsigned short;
    int t = threadIdx.x;
    if (blockIdx.x < EBH) {
        int e = blockIdx.x * 256 + t;
        if (e < NEDGES) perm[e] = (ushort)atomicAdd(&counts[dst[e]], 1);
    } else if (blockIdx.x < EBH + NPACK) {
        int idx = (blockIdx.x - EBH) * 256 + t;  // 0..163839
        if (idx < 65536) {
            int n = idx >> 8, k = idx & 255;
            Bt0[idx] = f2bf(W0[k * 256 + n]);
        } else if (idx < 131072) {
            int j = idx - 65536;
            int n = j >> 8, k = j & 255;
            Bt1[j] = f2bf(W1[k * 256 + n]);
        } else {
            int j = idx - 131072;
            int n = j >> 8, k = j & 255;
            Bt2[j] = f2bf(n < 64 ? W2[k * 64 + n] : Wr[k * 64 + (n - 64)]);
        }
    } else {
        size_t j = (size_t)(blockIdx.x - EBH - NPACK) * 4096 + t * 16;  // 3125*4096 = 12.8M exact
        float4 a0 = *reinterpret_cast<const float4*>(x + j);
        float4 a1 = *reinterpret_cast<const float4*>(x + j + 4);
        float4 a2 = *reinterpret_cast<const float4*>(x + j + 8);
        float4 a3 = *reinterpret_cast<const float4*>(x + j + 12);
        union { ushort8v v; ushort u[8]; } p0, p1;
        p0.u[0] = f2bf(a0.x); p0.u[1] = f2bf(a0.y); p0.u[2] = f2bf(a0.z); p0.u[3] = f2bf(a0.w);
        p0.u[4] = f2bf(a1.x); p0.u[5] = f2bf(a1.y); p0.u[6] = f2bf(a1.z); p0.u[7] = f2bf(a1.w);
        p1.u[0] = f2bf(a2.x); p1.u[1] = f2bf(a2.y); p1.u[2] = f2bf(a2.z); p1.u[3] = f2bf(a2.w);
        p1.u[4] = f2bf(a3.x); p1.u[5] = f2bf(a3.y); p1.u[6] = f2bf(a3.z); p1.u[7] = f2bf(a3.w);
        *reinterpret_cast<ushort8v*>(xb + j) = p0.v;
        *reinterpret_cast<ushort8v*>(xb + j + 8) = p1.v;
    }
}

__global__ __launch_bounds__(256) void scan_partial(const int* __restrict__ counts,
                                                    int* __restrict__ bsum, int Nn) {
    int b = blockIdx.x, t = threadIdx.x;
    int base = b * 1024;
    int v = 0;
#pragma unroll
    for (int i = 0; i < 4; ++i) {
        int idx = base + t + 256 * i;
        if (idx < Nn) v += counts[idx];
    }
    for (int o = 32; o; o >>= 1) v += __shfl_xor(v, o);
    __shared__ int ws[4];
    if ((t & 63) == 0) ws[t >> 6] = v;
    __syncthreads();
    if (t == 0) bsum[b] = ws[0] + ws[1] + ws[2] + ws[3];
}

__global__ __launch_bounds__(256) void scan_final(const int* __restrict__ counts,
                                                  const int* __restrict__ bsum,
                                                  int* __restrict__ row_start, int Nn, int nB) {
    __shared__ int off_s;
    __shared__ int tsum[256];
    int b = blockIdx.x, t = threadIdx.x;
    if (t == 0) {
        int o = 0;
        for (int i = 0; i < b; ++i) o += bsum[i];
        off_s = o;
    }
    int base = b * 1024 + t * 4;
    int c0 = 0, c1 = 0, c2 = 0, c3 = 0;
    if (base + 3 < Nn) {
        int4 c = *reinterpret_cast<const int4*>(counts + base);
        c0 = c.x; c1 = c.y; c2 = c.z; c3 = c.w;
    } else {
        if (base + 0 < Nn) c0 = counts[base + 0];
        if (base + 1 < Nn) c1 = counts[base + 1];
        if (base + 2 < Nn) c2 = counts[base + 2];
        if (base + 3 < Nn) c3 = counts[base + 3];
    }
    int s0 = c0, s1 = s0 + c1, s2 = s1 + c2, s3 = s2 + c3;
    tsum[t] = s3;
    __syncthreads();
    for (int o = 1; o < 256; o <<= 1) {
        int u = (t >= o) ? tsum[t - o] : 0;
        __syncthreads();
        tsum[t] += u;
        __syncthreads();
    }
    int o = off_s + tsum[t] - s3;
    if (base + 3 < Nn) {
        *reinterpret_cast<int4*>(row_start + base) = make_int4(o, o + s0, o + s1, o + s2);
    } else {
        if (base + 0 < Nn) row_start[base + 0] = o;
        if (base + 1 < Nn) row_start[base + 1] = o + s0;
        if (base + 2 < Nn) row_start[base + 2] = o + s1;
        if (base + 3 < Nn) row_start[base + 3] = o + s2;
    }
    if (b == nB - 1 && t == 255) row_start[Nn] = off_s + tsum[255];
}

// ---- 256-thread MFMA GEMM, 64x256 per block (4 waves, 1x4); 782 blocks ≈ 3/CU ----
// Smaller M-tile trades per-block efficiency for cross-block latency hiding: 4 blocks/CU
// resident (40KB LDS each) so barrier drains overlap other blocks' staging/compute.
// SCAT=true: blocks [0,NBMW) do GEMM, [NBMW, NBMW+SCB) do CSR scatter (atomic-free via perm).
// featb written FLAT (col = wc*64 + f2*16 + li): lane-contiguous coalesced 2B stores.
template <bool SCAT>
__global__ __launch_bounds__(256) void gemm_wide(const ushort* __restrict__ Ab,
                                                 const ushort* __restrict__ Bt,
                                                 const float* __restrict__ al,
                                                 const float* __restrict__ ar,
                                                 ushort* __restrict__ featb,
                                                 float* __restrict__ el, float* __restrict__ er,
                                                 int Nrows,
                                                 const int* __restrict__ srcv,
                                                 const int* __restrict__ dstv,
                                                 const int* __restrict__ row_start,
                                                 const ushort* __restrict__ perm,
                                                 ushort* __restrict__ csr_src) {
    using bf16x8 = __attribute__((ext_vector_type(8))) short;
    using f32x4 = __attribute__((ext_vector_type(4))) float;
    __shared__ ushort As[4096];   // 64 rows x 64 k
    __shared__ ushort Bs[16384];  // 256 cols x 64 k
    if constexpr (SCAT) {
        if (blockIdx.x >= NBMW) {
            int e = (blockIdx.x - NBMW) * 256 + threadIdx.x;
            if (e < NEDGES) {
                int d = dstv[e];
                csr_src[row_start[d] + perm[e]] = (ushort)srcv[e];
            }
            return;
        }
    }
    const int tid = threadIdx.x;
    const int lane = tid & 63;
    const int wave = tid >> 6;      // 0..3
    const int wc = wave;            // wave grid 1x4: 64 rows x 64 cols per wave
    const int q = lane >> 4, li = lane & 15;
    const int r0 = blockIdx.x * 64;

    f32x4 acc[4][4];
#pragma unroll
    for (int i = 0; i < 4; ++i)
#pragma unroll
        for (int j = 0; j < 4; ++j) acc[i][j] = (f32x4){0.f, 0.f, 0.f, 0.f};

    for (int kk = 0; kk < 256; kk += 64) {
        __syncthreads();
#pragma unroll
        for (int j = 0; j < 2; ++j) {
            int c = wave * 128 + j * 64 + lane;   // 512 chunks x 16B = 8KB
            int mr = c & 15, kg = (c >> 4) & 7, mf = c >> 7;
            const ushort* gp = Ab + (size_t)(r0 + mf * 16 + mr) * 256 + kk + kg * 8;
            void* lp = (char*)As + (size_t)(wave * 2 + j) * 1024;
            __builtin_amdgcn_global_load_lds((gptr_t)gp, (lptr_t)lp, 16, 0, 0);
        }
#pragma unroll
        for (int j = 0; j < 8; ++j) {
            int c = wave * 512 + j * 64 + lane;   // 2048 chunks x 16B = 32KB
            int nr = c & 15, kg = (c >> 4) & 7, nf = c >> 7;
            const ushort* gp = Bt + (size_t)(nf * 16 + nr) * 256 + kk + kg * 8;
            void* lp = (char*)Bs + (size_t)(wave * 8 + j) * 1024;
            __builtin_amdgcn_global_load_lds((gptr_t)gp, (lptr_t)lp, 16, 0, 0);
        }
        __syncthreads();
#pragma unroll
        for (int t = 0; t < 2; ++t) {
            const int kc = t * 4 + q;
            bf16x8 af[4], bfv[4];
#pragma unroll
            for (int f = 0; f < 4; ++f) {
                af[f] = *reinterpret_cast<const bf16x8*>(
                    &As[((f * 8 + kc) * 16 + li) * 8]);
                bfv[f] = *reinterpret_cast<const bf16x8*>(
                    &Bs[(((wc * 4 + f) * 8 + kc) * 16 + li) * 8]);
            }
#pragma unroll
            for (int f = 0; f < 4; ++f)
#pragma unroll
                for (int f2 = 0; f2 < 4; ++f2)
                    acc[f][f2] =
                        __builtin_amdgcn_mfma_f32_16x16x32_bf16(af[f], bfv[f2], acc[f][f2], 0, 0, 0);
        }
    }

    float alv[4], arv[4];
#pragma unroll
    for (int f2 = 0; f2 < 4; ++f2) {
        alv[f2] = al[wc * 64 + f2 * 16 + li];
        arv[f2] = ar[wc * 64 + f2 * 16 + li];
    }
#pragma unroll
    for (int f = 0; f < 4; ++f) {
#pragma unroll
        for (int r = 0; r < 4; ++r) {
            int row = r0 + f * 16 + q * 4 + r;
            bool ok = row < Nrows;
            float elp = 0.f, erp = 0.f;
#pragma unroll
            for (int f2 = 0; f2 < 4; ++f2) {
                float v = acc[f][f2][r];
                elp = fmaf(v, alv[f2], elp);
                erp = fmaf(v, arv[f2], erp);
                if (ok) featb[(size_t)row * 256 + wc * 64 + f2 * 16 + li] = f2bf(v);
            }
#pragma unroll
            for (int o = 1; o < 16; o <<= 1) {
                elp += __shfl_xor(elp, o);
                erp += __shfl_xor(erp, o);
            }
            if (ok && li == 0) {
                el[row * 4 + wc] = elp;
                er[row * 4 + wc] = erp;
            }
        }
    }
}

// ---- layer-2 GEMM: 256 threads, 128x128 ----
__global__ __launch_bounds__(256) void gemm_l2(const ushort* __restrict__ Ab,
                                               const ushort* __restrict__ Bt,
                                               const float* __restrict__ al,
                                               const float* __restrict__ ar,
                                               ushort* __restrict__ featb,
                                               float* __restrict__ el, float* __restrict__ er,
                                               float* __restrict__ resid, int Nrows) {
    using bf16x8 = __attribute__((ext_vector_type(8))) short;
    using f32x4 = __attribute__((ext_vector_type(4))) float;
    __shared__ ushort As[8192];
    __shared__ ushort Bs[8192];
    const int tid = threadIdx.x;
    const int lane = tid & 63;
    const int wave = tid >> 6;
    const int wr = wave >> 1, wc = wave & 1;
    const int q = lane >> 4, li = lane & 15;
    const int r0 = blockIdx.x * 128;

    f32x4 acc[4][4];
#pragma unroll
    for (int i = 0; i < 4; ++i)
#pragma unroll
        for (int j = 0; j < 4; ++j) acc[i][j] = (f32x4){0.f, 0.f, 0.f, 0.f};

    for (int kk = 0; kk < 256; kk += 64) {
        __syncthreads();
#pragma unroll
        for (int j = 0; j < 4; ++j) {
            int c = (wave * 4 + j) * 64 + lane;
            int mr = c & 15, kg = (c >> 4) & 7, mf = c >> 7;
            const ushort* gp = Ab + (size_t)(r0 + mf * 16 + mr) * 256 + kk + kg * 8;
            void* lp = (char*)As + (size_t)(wave * 4 + j) * 1024;
            __builtin_amdgcn_global_load_lds((gptr_t)gp, (lptr_t)lp, 16, 0, 0);
        }
#pragma unroll
        for (int j = 0; j < 4; ++j) {
            int c = (wave * 4 + j) * 64 + lane;
            int nr = c & 15, kg = (c >> 4) & 7, nf = c >> 7;
            const ushort* gp = Bt + (size_t)(nf * 16 + nr) * 256 + kk + kg * 8;
            void* lp = (char*)Bs + (size_t)(wave * 4 + j) * 1024;
            __builtin_amdgcn_global_load_lds((gptr_t)gp, (lptr_t)lp, 16, 0, 0);
        }
        __syncthreads();
#pragma unroll
        for (int t = 0; t < 2; ++t) {
            const int kc = t * 4 + q;
            bf16x8 af[4], bfv[4];
#pragma unroll
            for (int f = 0; f < 4; ++f) {
                af[f] = *reinterpret_cast<const bf16x8*>(
                    &As[(((wr * 4 + f) * 8 + kc) * 16 + li) * 8]);
                bfv[f] = *reinterpret_cast<const bf16x8*>(
                    &Bs[(((wc * 4 + f) * 8 + kc) * 16 + li) * 8]);
            }
#pragma unroll
            for (int f = 0; f < 4; ++f)
#pragma unroll
                for (int f2 = 0; f2 < 4; ++f2)
                    acc[f][f2] =
                        __builtin_amdgcn_mfma_f32_16x16x32_bf16(af[f], bfv[f2], acc[f][f2], 0, 0, 0);
        }
    }

    if (wc == 0) {
        float alv[4], arv[4];
#pragma unroll
        for (int f2 = 0; f2 < 4; ++f2) {
            alv[f2] = al[f2 * 16 + li];
            arv[f2] = ar[f2 * 16 + li];
        }
#pragma unroll
        for (int f = 0; f < 4; ++f) {
#pragma unroll
            for (int r = 0; r < 4; ++r) {
                int row = r0 + wr * 64 + f * 16 + q * 4 + r;
                bool ok = row < Nrows;
                float elp = 0.f, erp = 0.f;
#pragma unroll
                for (int f2 = 0; f2 < 4; ++f2) {
                    float v = acc[f][f2][r];
                    elp = fmaf(v, alv[f2], elp);
                    erp = fmaf(v, arv[f2], erp);
                    if (ok) featb[(size_t)row * 64 + f2 * 16 + li] = f2bf(v);
                }
#pragma unroll
                for (int o = 1; o < 16; o <<= 1) {
                    elp += __shfl_xor(elp, o);
                    erp += __shfl_xor(erp, o);
                }
                if (ok && li == 0) {
                    el[row] = elp;
                    er[row] = erp;
                }
            }
        }
    } else {
#pragma unroll
        for (int f = 0; f < 4; ++f) {
#pragma unroll
            for (int r = 0; r < 4; ++r) {
                int row = r0 + wr * 64 + f * 16 + q * 4 + r;
                if (row < Nrows) {
#pragma unroll
                    for (int f2 = 0; f2 < 4; ++f2)
                        resid[(size_t)row * 64 + f2 * 16 + li] = acc[f][f2][r];
                }
            }
        }
    }
}

// ---------------- agg H=4: 2 nodes per wave (2x32-lane groups), row-broadcast ----------------
// FLAT featb (col = h*64+d). Lane li owns cols [li*8, li*8+8) -> single head h = li>>3:
// scalar per-edge weight, one rcp per lane, 16B-contiguous resid/bias/out.
// 8-deep MLP (proven optimum: 4->8 = -10%, 16 = regress via codegen/occupancy).
// Tail entries are staged with w=0/off=0 -> harmless hot row-0 loads, zero contribution.
template <int RES, bool ACT>
__global__ __launch_bounds__(256) void agg4_kernel(
    const ushort* __restrict__ featb, const float* __restrict__ el,
    const float* __restrict__ er, const int* __restrict__ row_start,
    const ushort* __restrict__ csr_src, const ushort* __restrict__ resbuf,
    const float* __restrict__ bias, ushort* __restrict__ out, int Nn) {
    using ushort8v = __attribute__((ext_vector_type(8))) unsigned short;
    __shared__ float4 wbuf[4][2][32];
    __shared__ int obuf[4][2][32];
    const int wv = threadIdx.x >> 6, lane = threadIdx.x & 63;
    const int g = lane >> 5, li = lane & 31;
    const int hsel = li >> 3;                      // lane's head
    const int node = blockIdx.x * 8 + wv * 2 + g;  // 6250*8 == 50000 exact

    float4 bias0 = *reinterpret_cast<const float4*>(bias + li * 8);
    float4 bias1 = *reinterpret_cast<const float4*>(bias + li * 8 + 4);

    const int begin = row_start[node], end = row_start[node + 1];
    const float4 ern = *(reinterpret_cast<const float4*>(er) + node);
    const ushort* fb = featb + li * 8;
    const float* wflat = reinterpret_cast<const float*>(&wbuf[wv][g][0]);

    float dsum[4] = {0.f, 0.f, 0.f, 0.f};
    float acc[8] = {0.f, 0.f, 0.f, 0.f, 0.f, 0.f, 0.f, 0.f};

    int c = begin;
    int rem = end - begin;
    int remo = __shfl_xor(rem, 32);       // other group's remaining (group-uniform values)
    int nmax = rem > remo ? rem : remo;   // wave-uniform loop bound

    while (nmax > 0) {
        int nE = rem < 0 ? 0 : (rem < 32 ? rem : 32);
        int nEmax = nmax < 32 ? nmax : 32;
        float4 w = make_float4(0.f, 0.f, 0.f, 0.f);
        int s = 0;
        if (li < nE) {
            s = csr_src[c + li];
            float4 e4 = *(reinterpret_cast<const float4*>(el) + s);
            w.x = __expf(leaky(e4.x + ern.x));
            w.y = __expf(leaky(e4.y + ern.y));
            w.z = __expf(leaky(e4.z + ern.z));
            w.w = __expf(leaky(e4.w + ern.w));
        }
        dsum[0] += w.x; dsum[1] += w.y; dsum[2] += w.z; dsum[3] += w.w;
        obuf[wv][g][li] = s * 256;
        wbuf[wv][g][li] = w;
        __asm__ volatile("s_waitcnt lgkmcnt(0)" ::: "memory");

        // two-phase 8-deep batches: 8 loads in flight, then consume (scalar weight per lane's head)
        for (int e0 = 0; e0 < nEmax; e0 += 8) {
            ushort8v v[8];
#pragma unroll
            for (int k = 0; k < 8; ++k) {
                int off = obuf[wv][g][e0 + k];
                v[k] = *reinterpret_cast<const ushort8v*>(fb + off);
            }
#pragma unroll
            for (int k = 0; k < 8; ++k) {
                float we = wflat[(e0 + k) * 4 + hsel];
                acc[0] = fmaf(we, bf2f(v[k][0]), acc[0]);
                acc[1] = fmaf(we, bf2f(v[k][1]), acc[1]);
                acc[2] = fmaf(we, bf2f(v[k][2]), acc[2]);
                acc[3] = fmaf(we, bf2f(v[k][3]), acc[3]);
                acc[4] = fmaf(we, bf2f(v[k][4]), acc[4]);
                acc[5] = fmaf(we, bf2f(v[k][5]), acc[5]);
                acc[6] = fmaf(we, bf2f(v[k][6]), acc[6]);
                acc[7] = fmaf(we, bf2f(v[k][7]), acc[7]);
            }
        }
        __asm__ volatile("" ::: "memory");
        c += 32; rem -= 32; nmax -= 32;
    }

    // denom: sum staged w over the group's 32 lanes (xor <=16 stays within group)
#pragma unroll
    for (int h = 0; h < 4; ++h) {
        dsum[h] += __shfl_xor(dsum[h], 1);
        dsum[h] += __shfl_xor(dsum[h], 2);
        dsum[h] += __shfl_xor(dsum[h], 4);
        dsum[h] += __shfl_xor(dsum[h], 8);
        dsum[h] += __shfl_xor(dsum[h], 16);
    }
    // select own-head denominator without dynamic register indexing (rule #20)
    float dnlo = (li & 8) ? dsum[1] : dsum[0];
    float dnhi = (li & 8) ? dsum[3] : dsum[2];
    float dn = (li & 16) ? dnhi : dnlo;

    const bool has = end > begin;
    float inv = has ? __builtin_amdgcn_rcpf(dn) : 0.f;
    float o8[8];
#pragma unroll
    for (int j = 0; j < 8; ++j) o8[j] = acc[j] * inv;
    if constexpr (RES == 1) {
        ushort8v rv = *reinterpret_cast<const ushort8v*>(resbuf + (size_t)node * 256 + li * 8);
#pragma unroll
        for (int j = 0; j < 8; ++j) o8[j] += bf2f(rv[j]);
    }
    o8[0] += bias0.x; o8[1] += bias0.y; o8[2] += bias0.z; o8[3] += bias0.w;
    o8[4] += bias1.x; o8[5] += bias1.y; o8[6] += bias1.z; o8[7] += bias1.w;
    if constexpr (ACT) {
#pragma unroll
        for (int j = 0; j < 8; ++j) o8[j] = o8[j] > 0.f ? o8[j] : __expf(o8[j]) - 1.f;
    }
    union { ushort8v v; ushort u[8]; } pk;
#pragma unroll
    for (int j = 0; j < 8; ++j) pk.u[j] = f2bf(o8[j]);
    *reinterpret_cast<ushort8v*>(out + (size_t)node * 256 + li * 8) = pk.v;
}

// ---------------- agg H=1 (layer 2): 2 nodes per wave, row-broadcast, 8-deep MLP ----------------
__global__ __launch_bounds__(256) void agg1_kernel(
    const ushort* __restrict__ featb, const float* __restrict__ el,
    const float* __restrict__ er, const int* __restrict__ row_start,
    const ushort* __restrict__ csr_src, const float* __restrict__ resbuf,
    const float* __restrict__ bias, float* __restrict__ out, int Nn) {
    __shared__ float wbuf[4][2][32];
    __shared__ int obuf[4][2][32];
    const int wv = threadIdx.x >> 6, lane = threadIdx.x & 63;
    const int g = lane >> 5, li = lane & 31;
    const int node = blockIdx.x * 8 + wv * 2 + g;

    // lane li owns cols li*2, li*2+1
    float2 bv = *reinterpret_cast<const float2*>(bias + li * 2);

    const int begin = row_start[node], end = row_start[node + 1];
    const float ern = er[node];
    const ushort* fb = featb + li * 2;

    float dsum = 0.f;
    float acc0 = 0.f, acc1 = 0.f;

    int c = begin;
    int rem = end - begin;
    int remo = __shfl_xor(rem, 32);
    int nmax = rem > remo ? rem : remo;

    while (nmax > 0) {
        int nE = rem < 0 ? 0 : (rem < 32 ? rem : 32);
        int nEmax = nmax < 32 ? nmax : 32;
        float w = 0.f;
        int s = 0;
        if (li < nE) {
            s = csr_src[c + li];
            w = __expf(leaky(el[s] + ern));
        }
        dsum += w;
        obuf[wv][g][li] = s * 64;
        wbuf[wv][g][li] = w;
        __asm__ volatile("s_waitcnt lgkmcnt(0)" ::: "memory");

        for (int e0 = 0; e0 < nEmax; e0 += 8) {
            unsigned v[8];
#pragma unroll
            for (int k = 0; k < 8; ++k) {
                int off = obuf[wv][g][e0 + k];
                v[k] = *reinterpret_cast<const unsigned*>(fb + off);
            }
#pragma unroll
            for (int k = 0; k < 8; ++k) {
                float we = wbuf[wv][g][e0 + k];
                acc0 = fmaf(we, bf2f((ushort)(v[k] & 0xffffu)), acc0);
                acc1 = fmaf(we, bf2f((ushort)(v[k] >> 16)), acc1);
            }
        }
        __asm__ volatile("" ::: "memory");
        c += 32; rem -= 32; nmax -= 32;
    }

    dsum += __shfl_xor(dsum, 1);
    dsum += __shfl_xor(dsum, 2);
    dsum += __shfl_xor(dsum, 4);
    dsum += __shfl_xor(dsum, 8);
    dsum += __shfl_xor(dsum, 16);

    const bool has = end > begin;
    float2 rv = *reinterpret_cast<const float2*>(resbuf + (size_t)node * 64 + li * 2);
    float2 o2;
    o2.x = (has ? acc0 / dsum : 0.f) + rv.x + bv.x;
    o2.y = (has ? acc1 / dsum : 0.f) + rv.y + bv.y;
    *reinterpret_cast<float2*>(out + (size_t)node * 64 + li * 2) = o2;
}

// ---------------- launch ----------------
extern "C" void kernel_launch(void* const* d_in, const int* in_sizes, int n_in, void* d_out,
                              int out_size, void* d_ws, size_t ws_size, hipStream_t stream) {
    const float* x   = (const float*)d_in[0];
    const int* src   = (const int*)d_in[1];
    const int* dst   = (const int*)d_in[2];
    const float* W0  = (const float*)d_in[3];
    const float* al0 = (const float*)d_in[4];
    const float* ar0 = (const float*)d_in[5];
    const float* b0  = (const float*)d_in[6];
    const float* W1  = (const float*)d_in[7];
    const float* al1 = (const float*)d_in[8];
    const float* ar1 = (const float*)d_in[9];
    const float* b1  = (const float*)d_in[10];
    const float* W2  = (const float*)d_in[11];
    const float* al2 = (const float*)d_in[12];
    const float* ar2 = (const float*)d_in[13];
    const float* b2  = (const float*)d_in[14];
    const float* Wr2 = (const float*)d_in[15];
    float* out = (float*)d_out;

    char* w = (char*)d_ws;
    size_t off = 0;
    auto alloc = [&](size_t bytes) -> char* {
        char* p = w + off;
        off += (bytes + 255) & ~(size_t)255;
        return p;
    };
    ushort* xb      = (ushort*)alloc((size_t)NNODES * 256 * 2);
    ushort* hbuf    = (ushort*)alloc((size_t)NNODES * 256 * 2);
    ushort* featb   = (ushort*)alloc((size_t)NNODES * 256 * 2);
    float* resid    = (float*)alloc((size_t)NNODES * 64 * 4);
    float* el       = (float*)alloc((size_t)NNODES * 4 * 4);
    float* er       = (float*)alloc((size_t)NNODES * 4 * 4);
    ushort* Bt0     = (ushort*)alloc(65536 * 2);
    ushort* Bt1     = (ushort*)alloc(65536 * 2);
    ushort* Bt2     = (ushort*)alloc(32768 * 2);
    int* counts     = (int*)alloc((size_t)NNODES * 4);
    int* row_start  = (int*)alloc((size_t)(NNODES + 1) * 4);
    int* bsum       = (int*)alloc(64 * 4);
    ushort* csr_src = (ushort*)alloc((size_t)NEDGES * 2);
    ushort* perm    = (ushort*)alloc((size_t)NEDGES * 2);

    hipMemsetAsync(counts, 0, (size_t)NNODES * 4, stream);

    // front: hist(+perm) + pack + convert (overlapped independent work)
    front_kernel<<<EBH + NPACK + NCVT, 256, 0, stream>>>(dst, counts, perm, W0, W1, W2, Wr2,
                                                         Bt0, Bt1, Bt2, x, xb);
    scan_partial<<<NSB, 256, 0, stream>>>(counts, bsum, NNODES);
    scan_final<<<NSB, 256, 0, stream>>>(counts, bsum, row_start, NNODES, NSB);

    // layer 0 GEMM + scatter fused (atomic-free scatter hides under GEMM staging)
    gemm_wide<true><<<NBMW + SCB, 256, 0, stream>>>(xb, Bt0, al0, ar0, featb, el, er, NNODES,
                                                    src, dst, row_start, perm, csr_src);
    agg4_kernel<0, true><<<NBA, 256, 0, stream>>>(featb, el, er, row_start, csr_src,
                                                  nullptr, b0, hbuf, NNODES);
    // layer 1
    gemm_wide<false><<<NBMW, 256, 0, stream>>>(hbuf, Bt1, al1, ar1, featb, el, er, NNODES,
                                               nullptr, nullptr, nullptr, nullptr, nullptr);
    agg4_kernel<1, true><<<NBA, 256, 0, stream>>>(featb, el, er, row_start, csr_src,
                                                  hbuf, b1, hbuf, NNODES);
    // layer 2
    gemm_l2<<<NBML, 256, 0, stream>>>(hbuf, Bt2, al2, ar2, featb, el, er, resid, NNODES);
    agg1_kernel<<<NBA, 256, 0, stream>>>(featb, el, er, row_start, csr_src,
                                         resid, b2, out, NNODES);
}

// Round 11
// 367.057 us; speedup vs baseline: 1.0523x; 1.0523x over previous
//
#include <hip/hip_runtime.h>
#include <math.h>

#define NNODES 50000
#define NEDGES 800000
#define NSB 49       // scan blocks: ceil(50000/1024)
#define NPACK 640    // weight-pack blocks
#define NCVT 3125    // x->bf16 convert blocks: 50000*256/(256*16)
#define EBH 3125     // hist blocks: 800000/256
#define NBM 391      // gemm row-tile blocks: ceil(50000/128)
#define SCB 1563     // scatter blocks @512: ceil(800000/512)
#define NBA 6250     // agg4 blocks: 8 nodes/block (2 per wave), 6250*8 = 50000 exact
#define NBA1 3125    // agg1 blocks: 16 nodes/block (4 per wave), 3125*16 = 50000 exact

__device__ __forceinline__ float leaky(float x) { return x > 0.f ? x : 0.2f * x; }

__device__ __forceinline__ ushort f2bf(float f) {
    unsigned u = __float_as_uint(f);
    return (ushort)((u + 0x7fffu + ((u >> 16) & 1u)) >> 16);  // RNE
}
__device__ __forceinline__ float bf2f(ushort u) {
    return __uint_as_float((unsigned)u << 16);
}

typedef const __attribute__((address_space(1))) void* gptr_t;
typedef __attribute__((address_space(3))) void* lptr_t;

// featb layout (H=4 layers): FLAT head-major, col n = h*64 + d  (the GEMM's native
// B-column order). agg4 lane li consumes cols [li*8, li*8+8) -> all one head (li>>3),
// so the per-edge weight is a scalar and resid/bias/out are 16B-contiguous per lane.

// ---- front: hist(+perm) | weight pack | x->bf16 convert (independent work, one dispatch) ----
// Hist atomic's return value IS the within-node sequence number -> saved as perm[e],
// making the later CSR scatter atomic-free.
__global__ __launch_bounds__(256) void front_kernel(
    const int* __restrict__ dst, int* __restrict__ counts, ushort* __restrict__ perm,
    const float* __restrict__ W0, const float* __restrict__ W1, const float* __restrict__ W2,
    const float* __restrict__ Wr, ushort* __restrict__ Bt0, ushort* __restrict__ Bt1,
    ushort* __restrict__ Bt2, const float* __restrict__ x, ushort* __restrict__ xb) {
    using ushort8v = __attribute__((ext_vector_type(8))) unsigned short;
    int t = threadIdx.x;
    if (blockIdx.x < EBH) {
        int e = blockIdx.x * 256 + t;
        if (e < NEDGES) perm[e] = (ushort)atomicAdd(&counts[dst[e]], 1);
    } else if (blockIdx.x < EBH + NPACK) {
        int idx = (blockIdx.x - EBH) * 256 + t;  // 0..163839
        if (idx < 65536) {
            int n = idx >> 8, k = idx & 255;
            Bt0[idx] = f2bf(W0[k * 256 + n]);
        } else if (idx < 131072) {
            int j = idx - 65536;
            int n = j >> 8, k = j & 255;
            Bt1[j] = f2bf(W1[k * 256 + n]);
        } else {
            int j = idx - 131072;
            int n = j >> 8, k = j & 255;
            Bt2[j] = f2bf(n < 64 ? W2[k * 64 + n] : Wr[k * 64 + (n - 64)]);
        }
    } else {
        size_t j = (size_t)(blockIdx.x - EBH - NPACK) * 4096 + t * 16;  // 3125*4096 = 12.8M exact
        float4 a0 = *reinterpret_cast<const float4*>(x + j);
        float4 a1 = *reinterpret_cast<const float4*>(x + j + 4);
        float4 a2 = *reinterpret_cast<const float4*>(x + j + 8);
        float4 a3 = *reinterpret_cast<const float4*>(x + j + 12);
        union { ushort8v v; ushort u[8]; } p0, p1;
        p0.u[0] = f2bf(a0.x); p0.u[1] = f2bf(a0.y); p0.u[2] = f2bf(a0.z); p0.u[3] = f2bf(a0.w);
        p0.u[4] = f2bf(a1.x); p0.u[5] = f2bf(a1.y); p0.u[6] = f2bf(a1.z); p0.u[7] = f2bf(a1.w);
        p1.u[0] = f2bf(a2.x); p1.u[1] = f2bf(a2.y); p1.u[2] = f2bf(a2.z); p1.u[3] = f2bf(a2.w);
        p1.u[4] = f2bf(a3.x); p1.u[5] = f2bf(a3.y); p1.u[6] = f2bf(a3.z); p1.u[7] = f2bf(a3.w);
        *reinterpret_cast<ushort8v*>(xb + j) = p0.v;
        *reinterpret_cast<ushort8v*>(xb + j + 8) = p1.v;
    }
}

__global__ __launch_bounds__(256) void scan_partial(const int* __restrict__ counts,
                                                    int* __restrict__ bsum, int Nn) {
    int b = blockIdx.x, t = threadIdx.x;
    int base = b * 1024;
    int v = 0;
#pragma unroll
    for (int i = 0; i < 4; ++i) {
        int idx = base + t + 256 * i;
        if (idx < Nn) v += counts[idx];
    }
    for (int o = 32; o; o >>= 1) v += __shfl_xor(v, o);
    __shared__ int ws[4];
    if ((t & 63) == 0) ws[t >> 6] = v;
    __syncthreads();
    if (t == 0) bsum[b] = ws[0] + ws[1] + ws[2] + ws[3];
}

__global__ __launch_bounds__(256) void scan_final(const int* __restrict__ counts,
                                                  const int* __restrict__ bsum,
                                                  int* __restrict__ row_start, int Nn, int nB) {
    __shared__ int off_s;
    __shared__ int tsum[256];
    int b = blockIdx.x, t = threadIdx.x;
    if (t == 0) {
        int o = 0;
        for (int i = 0; i < b; ++i) o += bsum[i];
        off_s = o;
    }
    int base = b * 1024 + t * 4;
    int c0 = 0, c1 = 0, c2 = 0, c3 = 0;
    if (base + 3 < Nn) {
        int4 c = *reinterpret_cast<const int4*>(counts + base);
        c0 = c.x; c1 = c.y; c2 = c.z; c3 = c.w;
    } else {
        if (base + 0 < Nn) c0 = counts[base + 0];
        if (base + 1 < Nn) c1 = counts[base + 1];
        if (base + 2 < Nn) c2 = counts[base + 2];
        if (base + 3 < Nn) c3 = counts[base + 3];
    }
    int s0 = c0, s1 = s0 + c1, s2 = s1 + c2, s3 = s2 + c3;
    tsum[t] = s3;
    __syncthreads();
    for (int o = 1; o < 256; o <<= 1) {
        int u = (t >= o) ? tsum[t - o] : 0;
        __syncthreads();
        tsum[t] += u;
        __syncthreads();
    }
    int o = off_s + tsum[t] - s3;
    if (base + 3 < Nn) {
        *reinterpret_cast<int4*>(row_start + base) = make_int4(o, o + s0, o + s1, o + s2);
    } else {
        if (base + 0 < Nn) row_start[base + 0] = o;
        if (base + 1 < Nn) row_start[base + 1] = o + s0;
        if (base + 2 < Nn) row_start[base + 2] = o + s1;
        if (base + 3 < Nn) row_start[base + 3] = o + s2;
    }
    if (b == nB - 1 && t == 255) row_start[Nn] = off_s + tsum[255];
}

// ---- 512-thread MFMA GEMM, 128x256 per block; optional fused scatter blocks ----
// SCAT=true: blocks [0,NBM) do GEMM, [NBM, NBM+SCB) do CSR scatter (atomic-free via perm).
// featb written FLAT (col = wc*64 + f2*16 + li): lane-contiguous coalesced 2B stores.
template <bool SCAT>
__global__ __launch_bounds__(512) void gemm_wide(const ushort* __restrict__ Ab,
                                                 const ushort* __restrict__ Bt,
                                                 const float* __restrict__ al,
                                                 const float* __restrict__ ar,
                                                 ushort* __restrict__ featb,
                                                 float* __restrict__ el, float* __restrict__ er,
                                                 int Nrows,
                                                 const int* __restrict__ srcv,
                                                 const int* __restrict__ dstv,
                                                 const int* __restrict__ row_start,
                                                 const ushort* __restrict__ perm,
                                                 ushort* __restrict__ csr_src) {
    using bf16x8 = __attribute__((ext_vector_type(8))) short;
    using f32x4 = __attribute__((ext_vector_type(4))) float;
    __shared__ ushort As[8192];   // 128 rows x 64 k
    __shared__ ushort Bs[16384];  // 256 cols x 64 k
    if constexpr (SCAT) {
        if (blockIdx.x >= NBM) {
            int e = (blockIdx.x - NBM) * 512 + threadIdx.x;
            if (e < NEDGES) {
                int d = dstv[e];
                csr_src[row_start[d] + perm[e]] = (ushort)srcv[e];
            }
            return;
        }
    }
    const int tid = threadIdx.x;
    const int lane = tid & 63;
    const int wave = tid >> 6;
    const int wr = wave >> 2, wc = wave & 3;
    const int q = lane >> 4, li = lane & 15;
    const int r0 = blockIdx.x * 128;

    f32x4 acc[4][4];
#pragma unroll
    for (int i = 0; i < 4; ++i)
#pragma unroll
        for (int j = 0; j < 4; ++j) acc[i][j] = (f32x4){0.f, 0.f, 0.f, 0.f};

    for (int kk = 0; kk < 256; kk += 64) {
        __syncthreads();
#pragma unroll
        for (int j = 0; j < 2; ++j) {
            int c = wave * 128 + j * 64 + lane;
            int mr = c & 15, kg = (c >> 4) & 7, mf = c >> 7;
            const ushort* gp = Ab + (size_t)(r0 + mf * 16 + mr) * 256 + kk + kg * 8;
            void* lp = (char*)As + (size_t)(wave * 2 + j) * 1024;
            __builtin_amdgcn_global_load_lds((gptr_t)gp, (lptr_t)lp, 16, 0, 0);
        }
#pragma unroll
        for (int j = 0; j < 4; ++j) {
            int c = wave * 256 + j * 64 + lane;
            int nr = c & 15, kg = (c >> 4) & 7, nf = c >> 7;
            const ushort* gp = Bt + (size_t)(nf * 16 + nr) * 256 + kk + kg * 8;
            void* lp = (char*)Bs + (size_t)(wave * 4 + j) * 1024;
            __builtin_amdgcn_global_load_lds((gptr_t)gp, (lptr_t)lp, 16, 0, 0);
        }
        __syncthreads();
#pragma unroll
        for (int t = 0; t < 2; ++t) {
            const int kc = t * 4 + q;
            bf16x8 af[4], bfv[4];
#pragma unroll
            for (int f = 0; f < 4; ++f) {
                af[f] = *reinterpret_cast<const bf16x8*>(
                    &As[(((wr * 4 + f) * 8 + kc) * 16 + li) * 8]);
                bfv[f] = *reinterpret_cast<const bf16x8*>(
                    &Bs[(((wc * 4 + f) * 8 + kc) * 16 + li) * 8]);
            }
#pragma unroll
            for (int f = 0; f < 4; ++f)
#pragma unroll
                for (int f2 = 0; f2 < 4; ++f2)
                    acc[f][f2] =
                        __builtin_amdgcn_mfma_f32_16x16x32_bf16(af[f], bfv[f2], acc[f][f2], 0, 0, 0);
        }
    }

    float alv[4], arv[4];
#pragma unroll
    for (int f2 = 0; f2 < 4; ++f2) {
        alv[f2] = al[wc * 64 + f2 * 16 + li];
        arv[f2] = ar[wc * 64 + f2 * 16 + li];
    }
#pragma unroll
    for (int f = 0; f < 4; ++f) {
#pragma unroll
        for (int r = 0; r < 4; ++r) {
            int row = r0 + wr * 64 + f * 16 + q * 4 + r;
            bool ok = row < Nrows;
            float elp = 0.f, erp = 0.f;
#pragma unroll
            for (int f2 = 0; f2 < 4; ++f2) {
                float v = acc[f][f2][r];
                elp = fmaf(v, alv[f2], elp);
                erp = fmaf(v, arv[f2], erp);
                if (ok) featb[(size_t)row * 256 + wc * 64 + f2 * 16 + li] = f2bf(v);
            }
#pragma unroll
            for (int o = 1; o < 16; o <<= 1) {
                elp += __shfl_xor(elp, o);
                erp += __shfl_xor(erp, o);
            }
            if (ok && li == 0) {
                el[row * 4 + wc] = elp;
                er[row * 4 + wc] = erp;
            }
        }
    }
}

// ---- layer-2 GEMM: 256 threads, 128x128 ----
__global__ __launch_bounds__(256) void gemm_l2(const ushort* __restrict__ Ab,
                                               const ushort* __restrict__ Bt,
                                               const float* __restrict__ al,
                                               const float* __restrict__ ar,
                                               ushort* __restrict__ featb,
                                               float* __restrict__ el, float* __restrict__ er,
                                               float* __restrict__ resid, int Nrows) {
    using bf16x8 = __attribute__((ext_vector_type(8))) short;
    using f32x4 = __attribute__((ext_vector_type(4))) float;
    __shared__ ushort As[8192];
    __shared__ ushort Bs[8192];
    const int tid = threadIdx.x;
    const int lane = tid & 63;
    const int wave = tid >> 6;
    const int wr = wave >> 1, wc = wave & 1;
    const int q = lane >> 4, li = lane & 15;
    const int r0 = blockIdx.x * 128;

    f32x4 acc[4][4];
#pragma unroll
    for (int i = 0; i < 4; ++i)
#pragma unroll
        for (int j = 0; j < 4; ++j) acc[i][j] = (f32x4){0.f, 0.f, 0.f, 0.f};

    for (int kk = 0; kk < 256; kk += 64) {
        __syncthreads();
#pragma unroll
        for (int j = 0; j < 4; ++j) {
            int c = (wave * 4 + j) * 64 + lane;
            int mr = c & 15, kg = (c >> 4) & 7, mf = c >> 7;
            const ushort* gp = Ab + (size_t)(r0 + mf * 16 + mr) * 256 + kk + kg * 8;
            void* lp = (char*)As + (size_t)(wave * 4 + j) * 1024;
            __builtin_amdgcn_global_load_lds((gptr_t)gp, (lptr_t)lp, 16, 0, 0);
        }
#pragma unroll
        for (int j = 0; j < 4; ++j) {
            int c = (wave * 4 + j) * 64 + lane;
            int nr = c & 15, kg = (c >> 4) & 7, nf = c >> 7;
            const ushort* gp = Bt + (size_t)(nf * 16 + nr) * 256 + kk + kg * 8;
            void* lp = (char*)Bs + (size_t)(wave * 4 + j) * 1024;
            __builtin_amdgcn_global_load_lds((gptr_t)gp, (lptr_t)lp, 16, 0, 0);
        }
        __syncthreads();
#pragma unroll
        for (int t = 0; t < 2; ++t) {
            const int kc = t * 4 + q;
            bf16x8 af[4], bfv[4];
#pragma unroll
            for (int f = 0; f < 4; ++f) {
                af[f] = *reinterpret_cast<const bf16x8*>(
                    &As[(((wr * 4 + f) * 8 + kc) * 16 + li) * 8]);
                bfv[f] = *reinterpret_cast<const bf16x8*>(
                    &Bs[(((wc * 4 + f) * 8 + kc) * 16 + li) * 8]);
            }
#pragma unroll
            for (int f = 0; f < 4; ++f)
#pragma unroll
                for (int f2 = 0; f2 < 4; ++f2)
                    acc[f][f2] =
                        __builtin_amdgcn_mfma_f32_16x16x32_bf16(af[f], bfv[f2], acc[f][f2], 0, 0, 0);
        }
    }

    if (wc == 0) {
        float alv[4], arv[4];
#pragma unroll
        for (int f2 = 0; f2 < 4; ++f2) {
            alv[f2] = al[f2 * 16 + li];
            arv[f2] = ar[f2 * 16 + li];
        }
#pragma unroll
        for (int f = 0; f < 4; ++f) {
#pragma unroll
            for (int r = 0; r < 4; ++r) {
                int row = r0 + wr * 64 + f * 16 + q * 4 + r;
                bool ok = row < Nrows;
                float elp = 0.f, erp = 0.f;
#pragma unroll
                for (int f2 = 0; f2 < 4; ++f2) {
                    float v = acc[f][f2][r];
                    elp = fmaf(v, alv[f2], elp);
                    erp = fmaf(v, arv[f2], erp);
                    if (ok) featb[(size_t)row * 64 + f2 * 16 + li] = f2bf(v);
                }
#pragma unroll
                for (int o = 1; o < 16; o <<= 1) {
                    elp += __shfl_xor(elp, o);
                    erp += __shfl_xor(erp, o);
                }
                if (ok && li == 0) {
                    el[row] = elp;
                    er[row] = erp;
                }
            }
        }
    } else {
#pragma unroll
        for (int f = 0; f < 4; ++f) {
#pragma unroll
            for (int r = 0; r < 4; ++r) {
                int row = r0 + wr * 64 + f * 16 + q * 4 + r;
                if (row < Nrows) {
#pragma unroll
                    for (int f2 = 0; f2 < 4; ++f2)
                        resid[(size_t)row * 64 + f2 * 16 + li] = acc[f][f2][r];
                }
            }
        }
    }
}

// ---------------- agg H=4: 2 nodes per wave (2x32-lane groups), row-broadcast ----------------
// FLAT featb (col = h*64+d). Lane li owns cols [li*8, li*8+8) -> single head h = li>>3:
// scalar per-edge weight, one rcp per lane, 16B-contiguous resid/bias/out.
// 8-deep MLP (proven optimum: 4->8 = -10%, 16 = regress via codegen/occupancy).
// Tail entries are staged with w=0/off=0 -> harmless hot row-0 loads, zero contribution.
template <int RES, bool ACT>
__global__ __launch_bounds__(256) void agg4_kernel(
    const ushort* __restrict__ featb, const float* __restrict__ el,
    const float* __restrict__ er, const int* __restrict__ row_start,
    const ushort* __restrict__ csr_src, const ushort* __restrict__ resbuf,
    const float* __restrict__ bias, ushort* __restrict__ out, int Nn) {
    using ushort8v = __attribute__((ext_vector_type(8))) unsigned short;
    __shared__ float4 wbuf[4][2][32];
    __shared__ int obuf[4][2][32];
    const int wv = threadIdx.x >> 6, lane = threadIdx.x & 63;
    const int g = lane >> 5, li = lane & 31;
    const int hsel = li >> 3;                      // lane's head
    const int node = blockIdx.x * 8 + wv * 2 + g;  // 6250*8 == 50000 exact

    float4 bias0 = *reinterpret_cast<const float4*>(bias + li * 8);
    float4 bias1 = *reinterpret_cast<const float4*>(bias + li * 8 + 4);

    const int begin = row_start[node], end = row_start[node + 1];
    const float4 ern = *(reinterpret_cast<const float4*>(er) + node);
    const ushort* fb = featb + li * 8;
    const float* wflat = reinterpret_cast<const float*>(&wbuf[wv][g][0]);

    float dsum[4] = {0.f, 0.f, 0.f, 0.f};
    float acc[8] = {0.f, 0.f, 0.f, 0.f, 0.f, 0.f, 0.f, 0.f};

    int c = begin;
    int rem = end - begin;
    int remo = __shfl_xor(rem, 32);       // other group's remaining (group-uniform values)
    int nmax = rem > remo ? rem : remo;   // wave-uniform loop bound

    while (nmax > 0) {
        int nE = rem < 0 ? 0 : (rem < 32 ? rem : 32);
        int nEmax = nmax < 32 ? nmax : 32;
        float4 w = make_float4(0.f, 0.f, 0.f, 0.f);
        int s = 0;
        if (li < nE) {
            s = csr_src[c + li];
            float4 e4 = *(reinterpret_cast<const float4*>(el) + s);
            w.x = __expf(leaky(e4.x + ern.x));
            w.y = __expf(leaky(e4.y + ern.y));
            w.z = __expf(leaky(e4.z + ern.z));
            w.w = __expf(leaky(e4.w + ern.w));
        }
        dsum[0] += w.x; dsum[1] += w.y; dsum[2] += w.z; dsum[3] += w.w;
        obuf[wv][g][li] = s * 256;
        wbuf[wv][g][li] = w;
        __asm__ volatile("s_waitcnt lgkmcnt(0)" ::: "memory");

        // two-phase 8-deep batches: 8 loads in flight, then consume (scalar weight per lane's head)
        for (int e0 = 0; e0 < nEmax; e0 += 8) {
            ushort8v v[8];
#pragma unroll
            for (int k = 0; k < 8; ++k) {
                int off = obuf[wv][g][e0 + k];
                v[k] = *reinterpret_cast<const ushort8v*>(fb + off);
            }
#pragma unroll
            for (int k = 0; k < 8; ++k) {
                float we = wflat[(e0 + k) * 4 + hsel];
                acc[0] = fmaf(we, bf2f(v[k][0]), acc[0]);
                acc[1] = fmaf(we, bf2f(v[k][1]), acc[1]);
                acc[2] = fmaf(we, bf2f(v[k][2]), acc[2]);
                acc[3] = fmaf(we, bf2f(v[k][3]), acc[3]);
                acc[4] = fmaf(we, bf2f(v[k][4]), acc[4]);
                acc[5] = fmaf(we, bf2f(v[k][5]), acc[5]);
                acc[6] = fmaf(we, bf2f(v[k][6]), acc[6]);
                acc[7] = fmaf(we, bf2f(v[k][7]), acc[7]);
            }
        }
        __asm__ volatile("" ::: "memory");
        c += 32; rem -= 32; nmax -= 32;
    }

    // denom: sum staged w over the group's 32 lanes (xor <=16 stays within group)
#pragma unroll
    for (int h = 0; h < 4; ++h) {
        dsum[h] += __shfl_xor(dsum[h], 1);
        dsum[h] += __shfl_xor(dsum[h], 2);
        dsum[h] += __shfl_xor(dsum[h], 4);
        dsum[h] += __shfl_xor(dsum[h], 8);
        dsum[h] += __shfl_xor(dsum[h], 16);
    }
    // select own-head denominator without dynamic register indexing (rule #20)
    float dnlo = (li & 8) ? dsum[1] : dsum[0];
    float dnhi = (li & 8) ? dsum[3] : dsum[2];
    float dn = (li & 16) ? dnhi : dnlo;

    const bool has = end > begin;
    float inv = has ? __builtin_amdgcn_rcpf(dn) : 0.f;
    float o8[8];
#pragma unroll
    for (int j = 0; j < 8; ++j) o8[j] = acc[j] * inv;
    if constexpr (RES == 1) {
        ushort8v rv = *reinterpret_cast<const ushort8v*>(resbuf + (size_t)node * 256 + li * 8);
#pragma unroll
        for (int j = 0; j < 8; ++j) o8[j] += bf2f(rv[j]);
    }
    o8[0] += bias0.x; o8[1] += bias0.y; o8[2] += bias0.z; o8[3] += bias0.w;
    o8[4] += bias1.x; o8[5] += bias1.y; o8[6] += bias1.z; o8[7] += bias1.w;
    if constexpr (ACT) {
#pragma unroll
        for (int j = 0; j < 8; ++j) o8[j] = o8[j] > 0.f ? o8[j] : __expf(o8[j]) - 1.f;
    }
    union { ushort8v v; ushort u[8]; } pk;
#pragma unroll
    for (int j = 0; j < 8; ++j) pk.u[j] = f2bf(o8[j]);
    *reinterpret_cast<ushort8v*>(out + (size_t)node * 256 + li * 8) = pk.v;
}

// ---------------- agg H=1 (layer 2): 4 nodes per wave (4x16-lane groups), 8-deep MLP ------------
// Row = 64 cols x 2B = 128B -> 16 lanes x 8B. Lane li owns cols [li*4, li*4+4).
// Per-node prologue shared 4-ways; epilogue one float4 per lane.
__global__ __launch_bounds__(256) void agg1_kernel(
    const ushort* __restrict__ featb, const float* __restrict__ el,
    const float* __restrict__ er, const int* __restrict__ row_start,
    const ushort* __restrict__ csr_src, const float* __restrict__ resbuf,
    const float* __restrict__ bias, float* __restrict__ out, int Nn) {
    __shared__ float wbuf[4][4][16];
    __shared__ int obuf[4][4][16];
    const int wv = threadIdx.x >> 6, lane = threadIdx.x & 63;
    const int g = lane >> 4, li = lane & 15;
    const int node = blockIdx.x * 16 + wv * 4 + g;  // 3125*16 == 50000 exact

    float4 bv = *reinterpret_cast<const float4*>(bias + li * 4);

    const int begin = row_start[node], end = row_start[node + 1];
    const float ern = er[node];
    const ushort* fb = featb + li * 4;

    float dsum = 0.f;
    float a0 = 0.f, a1 = 0.f, a2 = 0.f, a3 = 0.f;

    int c = begin;
    int rem = end - begin;
    int m1 = max(rem, __shfl_xor(rem, 16));
    int nmax = max(m1, __shfl_xor(m1, 32));  // wave-uniform max over 4 groups

    while (nmax > 0) {
        int nE = rem < 0 ? 0 : (rem < 16 ? rem : 16);
        int nEmax = nmax < 16 ? nmax : 16;
        float w = 0.f;
        int s = 0;
        if (li < nE) {
            s = csr_src[c + li];
            w = __expf(leaky(el[s] + ern));
        }
        dsum += w;
        obuf[wv][g][li] = s * 64;
        wbuf[wv][g][li] = w;
        __asm__ volatile("s_waitcnt lgkmcnt(0)" ::: "memory");

        for (int e0 = 0; e0 < nEmax; e0 += 8) {
            uint2 v[8];
#pragma unroll
            for (int k = 0; k < 8; ++k) {
                int off = obuf[wv][g][e0 + k];
                v[k] = *reinterpret_cast<const uint2*>(fb + off);
            }
#pragma unroll
            for (int k = 0; k < 8; ++k) {
                float we = wbuf[wv][g][e0 + k];
                a0 = fmaf(we, bf2f((ushort)(v[k].x & 0xffffu)), a0);
                a1 = fmaf(we, bf2f((ushort)(v[k].x >> 16)), a1);
                a2 = fmaf(we, bf2f((ushort)(v[k].y & 0xffffu)), a2);
                a3 = fmaf(we, bf2f((ushort)(v[k].y >> 16)), a3);
            }
        }
        __asm__ volatile("" ::: "memory");
        c += 16; rem -= 16; nmax -= 16;
    }

    // denom: reduce over the group's 16 lanes (xor <=8 stays within group)
    dsum += __shfl_xor(dsum, 1);
    dsum += __shfl_xor(dsum, 2);
    dsum += __shfl_xor(dsum, 4);
    dsum += __shfl_xor(dsum, 8);

    const bool has = end > begin;
    float inv = has ? 1.f / dsum : 0.f;
    float4 rv = *reinterpret_cast<const float4*>(resbuf + (size_t)node * 64 + li * 4);
    float4 o4;
    o4.x = a0 * inv + rv.x + bv.x;
    o4.y = a1 * inv + rv.y + bv.y;
    o4.z = a2 * inv + rv.z + bv.z;
    o4.w = a3 * inv + rv.w + bv.w;
    *reinterpret_cast<float4*>(out + (size_t)node * 64 + li * 4) = o4;
}

// ---------------- launch ----------------
extern "C" void kernel_launch(void* const* d_in, const int* in_sizes, int n_in, void* d_out,
                              int out_size, void* d_ws, size_t ws_size, hipStream_t stream) {
    const float* x   = (const float*)d_in[0];
    const int* src   = (const int*)d_in[1];
    const int* dst   = (const int*)d_in[2];
    const float* W0  = (const float*)d_in[3];
    const float* al0 = (const float*)d_in[4];
    const float* ar0 = (const float*)d_in[5];
    const float* b0  = (const float*)d_in[6];
    const float* W1  = (const float*)d_in[7];
    const float* al1 = (const float*)d_in[8];
    const float* ar1 = (const float*)d_in[9];
    const float* b1  = (const float*)d_in[10];
    const float* W2  = (const float*)d_in[11];
    const float* al2 = (const float*)d_in[12];
    const float* ar2 = (const float*)d_in[13];
    const float* b2  = (const float*)d_in[14];
    const float* Wr2 = (const float*)d_in[15];
    float* out = (float*)d_out;

    char* w = (char*)d_ws;
    size_t off = 0;
    auto alloc = [&](size_t bytes) -> char* {
        char* p = w + off;
        off += (bytes + 255) & ~(size_t)255;
        return p;
    };
    ushort* xb      = (ushort*)alloc((size_t)NNODES * 256 * 2);
    ushort* hbuf    = (ushort*)alloc((size_t)NNODES * 256 * 2);
    ushort* featb   = (ushort*)alloc((size_t)NNODES * 256 * 2);
    float* resid    = (float*)alloc((size_t)NNODES * 64 * 4);
    float* el       = (float*)alloc((size_t)NNODES * 4 * 4);
    float* er       = (float*)alloc((size_t)NNODES * 4 * 4);
    ushort* Bt0     = (ushort*)alloc(65536 * 2);
    ushort* Bt1     = (ushort*)alloc(65536 * 2);
    ushort* Bt2     = (ushort*)alloc(32768 * 2);
    int* counts     = (int*)alloc((size_t)NNODES * 4);
    int* row_start  = (int*)alloc((size_t)(NNODES + 1) * 4);
    int* bsum       = (int*)alloc(64 * 4);
    ushort* csr_src = (ushort*)alloc((size_t)NEDGES * 2);
    ushort* perm    = (ushort*)alloc((size_t)NEDGES * 2);

    hipMemsetAsync(counts, 0, (size_t)NNODES * 4, stream);

    // front: hist(+perm) + pack + convert (overlapped independent work)
    front_kernel<<<EBH + NPACK + NCVT, 256, 0, stream>>>(dst, counts, perm, W0, W1, W2, Wr2,
                                                         Bt0, Bt1, Bt2, x, xb);
    scan_partial<<<NSB, 256, 0, stream>>>(counts, bsum, NNODES);
    scan_final<<<NSB, 256, 0, stream>>>(counts, bsum, row_start, NNODES, NSB);

    // layer 0 GEMM + scatter fused (atomic-free scatter hides under GEMM staging)
    gemm_wide<true><<<NBM + SCB, 512, 0, stream>>>(xb, Bt0, al0, ar0, featb, el, er, NNODES,
                                                   src, dst, row_start, perm, csr_src);
    agg4_kernel<0, true><<<NBA, 256, 0, stream>>>(featb, el, er, row_start, csr_src,
                                                  nullptr, b0, hbuf, NNODES);
    // layer 1
    gemm_wide<false><<<NBM, 512, 0, stream>>>(hbuf, Bt1, al1, ar1, featb, el, er, NNODES,
                                              nullptr, nullptr, nullptr, nullptr, nullptr);
    agg4_kernel<1, true><<<NBA, 256, 0, stream>>>(featb, el, er, row_start, csr_src,
                                                  hbuf, b1, hbuf, NNODES);
    // layer 2
    gemm_l2<<<NBM, 256, 0, stream>>>(hbuf, Bt2, al2, ar2, featb, el, er, resid, NNODES);
    agg1_kernel<<<NBA1, 256, 0, stream>>>(featb, el, er, row_start, csr_src,
                                          resid, b2, out, NNODES);
}